// Round 8
// baseline (109.718 us; speedup 1.0000x reference)
//
#include <hip/hip_runtime.h>
#include <hip/hip_bf16.h>

// Problem: B=32, S=512, P=512, D=768
//   M = B*S = 16384 tokens, N = P = 512 prototypes, K = D = 768
// out[0 .. M*N)            = distances  ||x_m - p_n||^2  (fp32)
// out[M*N .. M*N + N*K)    = prototypes (fp32 passthrough)
//
// R13 = R12 (16-wave, fragment-major B; 102.6us) + K-chunked dbuf A staging.
//   R12 vs R10: doubling waves/SIMD changed NOTHING -> the serial phase
//   structure (stage ~7us | K-loop ~7us | epilogue ~5us, each near its own
//   floor) is the limiter, not intra-phase parallelism. R13 overlaps staging
//   with MFMA inside the block: A staged in 6 chunks of K=128 (LDS dbuf
//   2 x 16.9KB = 33.8KB), chunk k+1 global loads issued BEFORE chunk k's
//   MFMAs, convert+ds_write after (T14). Per chunk: 512 MFMA/CU (~2480cyc)
//   covers ~900cyc HBM latency; chunk BW 8.4MB (~1.3us) = MFMA time. Only
//   chunk-0 stage + epilogue stay serial.
//   Unchanged from verified R12: grid 256 (1 block/CU, X read once, B
//   traffic 201MB), 1024 thr / 16 waves, wave = 64 tok x 32 protos
//   (acc[4][2]), fragment-major B depth-1 rotation, epilogue layout.

#define M_TOK 16384
#define N_PROT 512
#define K_DIM 768
#define BKC 128              // K-chunk staged in LDS (floats)
#define NKC (K_DIM / BKC)    // 6
#define NSK (K_DIM / 32)     // 24 MFMA k-steps
#define ASTR 132             // LDS row stride in bf16 units: 128 + 4 pad

typedef __attribute__((ext_vector_type(4))) float f32x4;
typedef __attribute__((ext_vector_type(8))) short bf16x8;

__device__ inline unsigned short f2bf(float f) {
    // round-to-nearest-even on the bit pattern (finite inputs)
    unsigned int u = __float_as_uint(f);
    u += 0x7fffu + ((u >> 16) & 1u);
    return (unsigned short)(u >> 16);
}

// One wave per prototype row: bf16 convert (fragment-major store) + ||p||^2
// + fp32 passthrough copy.  (unchanged from verified R10)
__global__ __launch_bounds__(256) void prep_b(
    const float* __restrict__ p,
    unsigned short* __restrict__ b_bf, float* __restrict__ p_sq,
    float* __restrict__ proto_out)
{
    const int row  = blockIdx.x * 4 + (threadIdx.x >> 6);
    const int lane = threadIdx.x & 63;

    const int g    = row >> 4;          // proto group 0..31
    const int l16p = row & 15;          // row within group

    const float4* src4 = (const float4*)(p + (size_t)row * K_DIM);
    float4* pout4 = (float4*)(proto_out + (size_t)row * K_DIM);

    float ssum = 0.0f;
#pragma unroll
    for (int j = 0; j < 3; ++j) {        // 192 float4 per row / 64 lanes
        const int idx = lane + j * 64;   // float4 index 0..191
        float4 v = src4[idx];
        ssum += v.x * v.x + v.y * v.y + v.z * v.z + v.w * v.w;
        ushort4 b;
        b.x = f2bf(v.x); b.y = f2bf(v.y); b.z = f2bf(v.z); b.w = f2bf(v.w);
        // fragment-major: element k -> block (g*24 + k>>5), slot
        // ((k>>3)&3)*16 + l16p (lane id), sub-offset k&7.
        const int k0   = idx * 4;               // first element of this ushort4
        const int kk   = k0 >> 5;               // k-step 0..23
        const int quad = (k0 >> 3) & 3;         // k-slice 0..3
        const int j0   = k0 & 7;                // 0 or 4
        const int dst  = (g * 24 + kk) * 512 + quad * 128 + l16p * 8 + j0;
        *(ushort4*)&b_bf[dst] = b;
        pout4[idx] = v;
    }
#pragma unroll
    for (int off = 32; off > 0; off >>= 1) ssum += __shfl_down(ssum, off);
    if (lane == 0) p_sq[row] = ssum;
}

__global__ __launch_bounds__(1024, 4) void dist_main(
    const float* __restrict__ X,             // [M,K] fp32 tokens
    const unsigned short* __restrict__ Bb,   // fragment-major bf16 protos (ws)
    const float* __restrict__ p_sq,          // [N] fp32
    float* __restrict__ out)                 // [M,N] fp32 distances
{
    __shared__ unsigned short lds_a[2][64 * ASTR];   // 2 x 16896 B = 33792 B
    __shared__ float lds_xsq[64];

    const int tid  = threadIdx.x;
    const int wave = tid >> 6;           // 0..15
    const int lane = tid & 63;
    const int bm   = blockIdx.x << 6;    // 64-row A stripe
    const int wn   = wave << 5;          // this wave's 32-col slice of N
    const int quad = lane >> 4;          // 0..3
    const int l16  = lane & 15;

    // ---- staging mapping: 1024 thr stage a 64x128 fp32 chunk ----
    // 2048 float4 / 1024 thr = 2 float4/thread, at float4 idx ac and ac+16.
    const int ar = tid >> 4;             // row 0..63
    const int ac = tid & 15;             // float4 col base 0..15
    const float* aptr = X + (size_t)(bm + ar) * K_DIM + ac * 4;

    float asq = 0.0f;

    // prologue: stage chunk 0
    {
        float4 v0 = *(const float4*)(aptr);
        float4 v1 = *(const float4*)(aptr + 64);
        asq += v0.x * v0.x + v0.y * v0.y + v0.z * v0.z + v0.w * v0.w;
        asq += v1.x * v1.x + v1.y * v1.y + v1.z * v1.z + v1.w * v1.w;
        ushort4 u0, u1;
        u0.x = f2bf(v0.x); u0.y = f2bf(v0.y); u0.z = f2bf(v0.z); u0.w = f2bf(v0.w);
        u1.x = f2bf(v1.x); u1.y = f2bf(v1.y); u1.z = f2bf(v1.z); u1.w = f2bf(v1.w);
        *(ushort4*)&lds_a[0][ar * ASTR + ac * 4]      = u0;
        *(ushort4*)&lds_a[0][ar * ASTR + ac * 4 + 64] = u1;
    }
    __syncthreads();

    // ---- fragment-major B streams: block (g*24+kk)*1KB, lane's 16B at lane*16
    const unsigned short* bp = Bb + (size_t)lane * 8;
    const int gbase = (wave << 1) * 24;          // (wave*2)*24

    bf16x8 bcur[2], bnxt[2];
#pragma unroll
    for (int nt = 0; nt < 2; ++nt)
        bcur[nt] = *(const bf16x8*)(bp + (size_t)(gbase + nt * 24) * 512);

    const f32x4 zero = {0.0f, 0.0f, 0.0f, 0.0f};
    f32x4 acc[4][2];
#pragma unroll
    for (int mt = 0; mt < 4; ++mt) {
        acc[mt][0] = zero; acc[mt][1] = zero;
    }

    for (int kc = 0; kc < NKC; ++kc) {
        // issue next A-chunk global loads early (hide under this chunk's MFMAs)
        float4 s0, s1;
        if (kc + 1 < NKC) {
            const float* ap = aptr + (kc + 1) * BKC;
            s0 = *(const float4*)(ap);
            s1 = *(const float4*)(ap + 64);
        }

#pragma unroll
        for (int ss = 0; ss < 4; ++ss) {
            const int kk = kc * 4 + ss;
            if (kk + 1 < NSK) {              // uniform scalar branch, depth-1
#pragma unroll
                for (int nt = 0; nt < 2; ++nt)
                    bnxt[nt] = *(const bf16x8*)(bp
                        + (size_t)((gbase + nt * 24) * 24 / 24 + nt * 0) * 0
                        + (size_t)(gbase + nt * 24 + kk + 1) * 512);
            }

            bf16x8 af[4];
#pragma unroll
            for (int mt = 0; mt < 4; ++mt)
                af[mt] = *(const bf16x8*)&lds_a[kc & 1]
                    [(mt * 16 + l16) * ASTR + ss * 32 + quad * 8];

#pragma unroll
            for (int mt = 0; mt < 4; ++mt) {
                acc[mt][0] = __builtin_amdgcn_mfma_f32_16x16x32_bf16(
                    af[mt], bcur[0], acc[mt][0], 0, 0, 0);
                acc[mt][1] = __builtin_amdgcn_mfma_f32_16x16x32_bf16(
                    af[mt], bcur[1], acc[mt][1], 0, 0, 0);
            }
            bcur[0] = bnxt[0]; bcur[1] = bnxt[1];
        }

        // convert + write next chunk into the other buffer, then one barrier
        if (kc + 1 < NKC) {
            unsigned short* aw = &lds_a[(kc + 1) & 1][ar * ASTR + ac * 4];
            asq += s0.x * s0.x + s0.y * s0.y + s0.z * s0.z + s0.w * s0.w;
            asq += s1.x * s1.x + s1.y * s1.y + s1.z * s1.z + s1.w * s1.w;
            ushort4 u0, u1;
            u0.x = f2bf(s0.x); u0.y = f2bf(s0.y); u0.z = f2bf(s0.z); u0.w = f2bf(s0.w);
            u1.x = f2bf(s1.x); u1.y = f2bf(s1.y); u1.z = f2bf(s1.z); u1.w = f2bf(s1.w);
            *(ushort4*)(aw)      = u0;
            *(ushort4*)(aw + 64) = u1;
        }
        __syncthreads();
    }

    // ---- x_sq: reduce over the 16 staging threads of each row ----
#pragma unroll
    for (int off = 1; off < 16; off <<= 1) asq += __shfl_xor(asq, off);
    if (ac == 0) lds_xsq[ar] = asq;
    __syncthreads();

    // ---- epilogue: C/D layout col = lane&15, row = quad*4 + i ----
    float ps[2];
#pragma unroll
    for (int nt = 0; nt < 2; ++nt) ps[nt] = p_sq[wn + nt * 16 + l16];

#pragma unroll
    for (int mt = 0; mt < 4; ++mt) {
#pragma unroll
        for (int i = 0; i < 4; ++i) {
            const int lr = mt * 16 + quad * 4 + i;   // local row 0..63
            const float xs = lds_xsq[lr];
            float* orow = out + (size_t)(bm + lr) * N_PROT + wn + l16;
#pragma unroll
            for (int nt = 0; nt < 2; ++nt)
                orow[nt * 16] = xs + ps[nt] - 2.0f * acc[mt][nt][i];
        }
    }
}

extern "C" void kernel_launch(void* const* d_in, const int* in_sizes, int n_in,
                              void* d_out, int out_size, void* d_ws, size_t ws_size,
                              hipStream_t stream) {
    const float* inputs = (const float*)d_in[0];   // [32,512,768] fp32
    const float* protos = (const float*)d_in[1];   // [512,768]    fp32
    float* out = (float*)d_out;
    float* proto_out = out + (size_t)M_TOK * N_PROT;   // second tuple element

    // ws layout: b_bf 512*768*2 = 786,432 B (fragment-major) ; p_sq 2,048 B
    char* ws = (char*)d_ws;
    unsigned short* b_bf = (unsigned short*)ws;
    float* p_sq = (float*)(ws + 786432);

    prep_b<<<128, 256, 0, stream>>>(protos, b_bf, p_sq, proto_out);
    dist_main<<<M_TOK / 64, 1024, 0, stream>>>(inputs, b_bf, p_sq, out);
}

// Round 10
// 107.740 us; speedup vs baseline: 1.0184x; 1.0184x over previous
//
#include <hip/hip_runtime.h>
#include <hip/hip_bf16.h>

// Problem: B=32, S=512, P=512, D=768
//   M = B*S = 16384 tokens, N = P = 512 prototypes, K = D = 768
// out[0 .. M*N)            = distances  ||x_m - p_n||^2  (fp32)
// out[M*N .. M*N + N*K)    = prototypes (fp32 passthrough)
//
// R15 = R14 resubmitted verbatim (Round-9 bench failed on infrastructure:
// "MI355X container failed twice" -- no kernel data came back).
//
// R14 = R12 (16-wave monolithic, fragment-major B; best at 102.6us) with
// TWO-SECTION K staging: stage A[:,0:384] as one full burst | barrier |
// issue A[:,384:768] loads to regs | K-loop section 0 (12 steps, ~3.5us)
// hides the in-flight loads | vmcnt-wait + convert + ds_write | barrier |
// K-loop section 1 | epilogue.
//   Why this and not R13's 6-chunk dbuf (which regressed): only 2 barriers
//   (not 6), staging keeps full 6-load burst ILP, the hide window is a
//   whole half-K loop (~3.5us >> HBM latency), same 97KB LDS (sections are
//   column ranges of ONE buffer, no dbuf). Known cost: vmcnt retires in
//   issue order, so the first ~2 B-prefetch waits of loop 0 stall on the
//   older s1 loads (~0.25us once) -- accepted vs ~4us staging hidden.
//   Unchanged from verified R12: grid 256 (1 block/CU, X read once, B
//   traffic 201MB), 1024 thr / 16 waves, wave = 64 tok x 32 protos
//   (acc[4][2]), fragment-major coalesced B depth-1 rotation, epilogue.

#define M_TOK 16384
#define N_PROT 512
#define K_DIM 768
#define BK 32
#define NSK (K_DIM / BK)     // 24 MFMA k-steps
#define KSEC 12              // k-steps per section (K=384)
#define ASTR (K_DIM + 8)     // 776: padded LDS row stride in bf16 units

typedef __attribute__((ext_vector_type(4))) float f32x4;
typedef __attribute__((ext_vector_type(8))) short bf16x8;

__device__ inline unsigned short f2bf(float f) {
    // round-to-nearest-even on the bit pattern (finite inputs)
    unsigned int u = __float_as_uint(f);
    u += 0x7fffu + ((u >> 16) & 1u);
    return (unsigned short)(u >> 16);
}

// One wave per prototype row: bf16 convert (fragment-major store) + ||p||^2
// + fp32 passthrough copy.  (unchanged from verified R10)
__global__ __launch_bounds__(256) void prep_b(
    const float* __restrict__ p,
    unsigned short* __restrict__ b_bf, float* __restrict__ p_sq,
    float* __restrict__ proto_out)
{
    const int row  = blockIdx.x * 4 + (threadIdx.x >> 6);
    const int lane = threadIdx.x & 63;

    const int g    = row >> 4;          // proto group 0..31
    const int l16p = row & 15;          // row within group

    const float4* src4 = (const float4*)(p + (size_t)row * K_DIM);
    float4* pout4 = (float4*)(proto_out + (size_t)row * K_DIM);

    float ssum = 0.0f;
#pragma unroll
    for (int j = 0; j < 3; ++j) {        // 192 float4 per row / 64 lanes
        const int idx = lane + j * 64;   // float4 index 0..191
        float4 v = src4[idx];
        ssum += v.x * v.x + v.y * v.y + v.z * v.z + v.w * v.w;
        ushort4 b;
        b.x = f2bf(v.x); b.y = f2bf(v.y); b.z = f2bf(v.z); b.w = f2bf(v.w);
        // fragment-major: element k -> block (g*24 + k>>5), slot
        // ((k>>3)&3)*16 + l16p (lane id), sub-offset k&7.
        const int k0   = idx * 4;               // first element of this ushort4
        const int kk   = k0 >> 5;               // k-step 0..23
        const int quad = (k0 >> 3) & 3;         // k-slice 0..3
        const int j0   = k0 & 7;                // 0 or 4
        const int dst  = (g * 24 + kk) * 512 + quad * 128 + l16p * 8 + j0;
        *(ushort4*)&b_bf[dst] = b;
        pout4[idx] = v;
    }
#pragma unroll
    for (int off = 32; off > 0; off >>= 1) ssum += __shfl_down(ssum, off);
    if (lane == 0) p_sq[row] = ssum;
}

__global__ __launch_bounds__(1024, 4) void dist_main(
    const float* __restrict__ X,             // [M,K] fp32 tokens
    const unsigned short* __restrict__ Bb,   // fragment-major bf16 protos (ws)
    const float* __restrict__ p_sq,          // [N] fp32
    float* __restrict__ out)                 // [M,N] fp32 distances
{
    __shared__ unsigned short lds_a[64 * ASTR];   // ~97 KB, full-K A stripe
    __shared__ float lds_xsq[64];

    const int tid  = threadIdx.x;
    const int wave = tid >> 6;           // 0..15
    const int lane = tid & 63;
    const int bm   = blockIdx.x << 6;    // 64-row A stripe
    const int wn   = wave << 5;          // this wave's 32-col slice of N
    const int quad = lane >> 4;          // 0..3
    const int l16  = lane & 15;

    // ---- staging mapping: 1024 thr, section = 64 rows x 96 float4 ----
    // per section: 6144 float4 / 1024 thr = 6 each, c4 = sec*96 + ac + 16*j
    const int ar = tid >> 4;             // row 0..63
    const int ac = tid & 15;             // float4 col base 0..15
    const float* aptr = X + (size_t)(bm + ar) * K_DIM;

    float asq = 0.0f;

    // ---- stage section 0 as one full burst (6 loads in flight) ----
#pragma unroll
    for (int j = 0; j < 6; ++j) {
        const int c4 = ac + 16 * j;      // float4 index 0..95
        float4 v = *(const float4*)(aptr + (size_t)c4 * 4);
        asq += v.x * v.x + v.y * v.y + v.z * v.z + v.w * v.w;
        ushort4 u;
        u.x = f2bf(v.x); u.y = f2bf(v.y); u.z = f2bf(v.z); u.w = f2bf(v.w);
        *(ushort4*)&lds_a[ar * ASTR + c4 * 4] = u;
    }
    __syncthreads();   // barrier 1: section 0 visible

    // ---- B init (issue BEFORE s1 so first MFMA isn't poisoned) ----
    const unsigned short* bp = Bb + (size_t)lane * 8;
    const int gbase = (wave << 1) * 24;          // (wave*2)*24

    bf16x8 bcur[2], bnxt[2];
#pragma unroll
    for (int nt = 0; nt < 2; ++nt)
        bcur[nt] = *(const bf16x8*)(bp + (size_t)(gbase + nt * 24) * 512);

    // ---- issue section-1 global loads; hidden under K-loop section 0 ----
    float4 s1[6];
#pragma unroll
    for (int j = 0; j < 6; ++j)
        s1[j] = *(const float4*)(aptr + (size_t)(96 + ac + 16 * j) * 4);

    const f32x4 zero = {0.0f, 0.0f, 0.0f, 0.0f};
    f32x4 acc[4][2];
#pragma unroll
    for (int mt = 0; mt < 4; ++mt) {
        acc[mt][0] = zero; acc[mt][1] = zero;
    }

    // ---- K-loop section 0: kc = 0..11 ----
    for (int kc = 0; kc < KSEC; ++kc) {
#pragma unroll
        for (int nt = 0; nt < 2; ++nt)
            bnxt[nt] = *(const bf16x8*)(bp
                + (size_t)(gbase + nt * 24 + kc + 1) * 512);

        bf16x8 af[4];
        const int k0 = kc * BK;
#pragma unroll
        for (int mt = 0; mt < 4; ++mt)
            af[mt] = *(const bf16x8*)&lds_a[(mt * 16 + l16) * ASTR + k0 + quad * 8];

#pragma unroll
        for (int mt = 0; mt < 4; ++mt) {
            acc[mt][0] = __builtin_amdgcn_mfma_f32_16x16x32_bf16(
                af[mt], bcur[0], acc[mt][0], 0, 0, 0);
            acc[mt][1] = __builtin_amdgcn_mfma_f32_16x16x32_bf16(
                af[mt], bcur[1], acc[mt][1], 0, 0, 0);
        }
        bcur[0] = bnxt[0]; bcur[1] = bnxt[1];
    }

    // ---- convert + write section 1 (loads retired during loop 0) ----
#pragma unroll
    for (int j = 0; j < 6; ++j) {
        float4 v = s1[j];
        asq += v.x * v.x + v.y * v.y + v.z * v.z + v.w * v.w;
        ushort4 u;
        u.x = f2bf(v.x); u.y = f2bf(v.y); u.z = f2bf(v.z); u.w = f2bf(v.w);
        *(ushort4*)&lds_a[ar * ASTR + (96 + ac + 16 * j) * 4] = u;
    }
    __syncthreads();   // barrier 2: section 1 visible

    // ---- K-loop section 1: kc = 12..23 ----
    for (int kc = KSEC; kc < NSK; ++kc) {
        if (kc + 1 < NSK) {
#pragma unroll
            for (int nt = 0; nt < 2; ++nt)
                bnxt[nt] = *(const bf16x8*)(bp
                    + (size_t)(gbase + nt * 24 + kc + 1) * 512);
        }

        bf16x8 af[4];
        const int k0 = kc * BK;
#pragma unroll
        for (int mt = 0; mt < 4; ++mt)
            af[mt] = *(const bf16x8*)&lds_a[(mt * 16 + l16) * ASTR + k0 + quad * 8];

#pragma unroll
        for (int mt = 0; mt < 4; ++mt) {
            acc[mt][0] = __builtin_amdgcn_mfma_f32_16x16x32_bf16(
                af[mt], bcur[0], acc[mt][0], 0, 0, 0);
            acc[mt][1] = __builtin_amdgcn_mfma_f32_16x16x32_bf16(
                af[mt], bcur[1], acc[mt][1], 0, 0, 0);
        }
        bcur[0] = bnxt[0]; bcur[1] = bnxt[1];
    }

    // ---- x_sq: reduce over the 16 staging threads of each row ----
#pragma unroll
    for (int off = 1; off < 16; off <<= 1) asq += __shfl_xor(asq, off);
    if (ac == 0) lds_xsq[ar] = asq;
    __syncthreads();

    // ---- epilogue: C/D layout col = lane&15, row = quad*4 + i ----
    float ps[2];
#pragma unroll
    for (int nt = 0; nt < 2; ++nt) ps[nt] = p_sq[wn + nt * 16 + l16];

#pragma unroll
    for (int mt = 0; mt < 4; ++mt) {
#pragma unroll
        for (int i = 0; i < 4; ++i) {
            const int lr = mt * 16 + quad * 4 + i;   // local row 0..63
            const float xs = lds_xsq[lr];
            float* orow = out + (size_t)(bm + lr) * N_PROT + wn + l16;
#pragma unroll
            for (int nt = 0; nt < 2; ++nt)
                orow[nt * 16] = xs + ps[nt] - 2.0f * acc[mt][nt][i];
        }
    }
}

extern "C" void kernel_launch(void* const* d_in, const int* in_sizes, int n_in,
                              void* d_out, int out_size, void* d_ws, size_t ws_size,
                              hipStream_t stream) {
    const float* inputs = (const float*)d_in[0];   // [32,512,768] fp32
    const float* protos = (const float*)d_in[1];   // [512,768]    fp32
    float* out = (float*)d_out;
    float* proto_out = out + (size_t)M_TOK * N_PROT;   // second tuple element

    // ws layout: b_bf 512*768*2 = 786,432 B (fragment-major) ; p_sq 2,048 B
    char* ws = (char*)d_ws;
    unsigned short* b_bf = (unsigned short*)ws;
    float* p_sq = (float*)(ws + 786432);

    prep_b<<<128, 256, 0, stream>>>(protos, b_bf, p_sq, proto_out);
    dist_main<<<M_TOK / 64, 1024, 0, stream>>>(inputs, b_bf, p_sq, out);
}

// Round 11
// 103.790 us; speedup vs baseline: 1.0571x; 1.0381x over previous
//
#include <hip/hip_runtime.h>
#include <hip/hip_bf16.h>

// Problem: B=32, S=512, P=512, D=768
//   M = B*S = 16384 tokens, N = P = 512 prototypes, K = D = 768
// out[0 .. M*N)            = distances  ||x_m - p_n||^2  (fp32)
// out[M*N .. M*N + N*K)    = prototypes (fp32 passthrough)
//
// R16 = R14 + sched_barrier(0) pinning the section-1 load issue.
//   R14 (107.7us vs R12's 102.6) likely failed because hipcc SANK the six
//   s1 global loads down to their first use (after K-loop section 0) --
//   nothing in source pins the issue point, and sinking shortens register
//   lifetimes. That degenerates R14 into "R12 + extra barrier + half-depth
//   staging bursts" = the +5us measured. SCHED_BARRIER(0) has unmodeled
//   side effects: neither the scheduler nor MachineSinking may move the
//   loads past it, so they must ISSUE before section-0's MFMAs while their
//   WAIT stays at first use (after loop 0). Guide rule #18/T19 pattern.
//   Issue order kept from R14: B-init first, then s1, so iteration-0's MFMA
//   doesn't wait on s1 (only iteration-1's counted vmcnt does, once).
//   Everything else byte-identical to R14/R15 (16-wave monolithic, fragment-
//   major coalesced B, grid 256, 1 block/CU, acc[4][2], 3 barriers).

#define M_TOK 16384
#define N_PROT 512
#define K_DIM 768
#define BK 32
#define NSK (K_DIM / BK)     // 24 MFMA k-steps
#define KSEC 12              // k-steps per section (K=384)
#define ASTR (K_DIM + 8)     // 776: padded LDS row stride in bf16 units

typedef __attribute__((ext_vector_type(4))) float f32x4;
typedef __attribute__((ext_vector_type(8))) short bf16x8;

__device__ inline unsigned short f2bf(float f) {
    // round-to-nearest-even on the bit pattern (finite inputs)
    unsigned int u = __float_as_uint(f);
    u += 0x7fffu + ((u >> 16) & 1u);
    return (unsigned short)(u >> 16);
}

// One wave per prototype row: bf16 convert (fragment-major store) + ||p||^2
// + fp32 passthrough copy.  (unchanged from verified R10)
__global__ __launch_bounds__(256) void prep_b(
    const float* __restrict__ p,
    unsigned short* __restrict__ b_bf, float* __restrict__ p_sq,
    float* __restrict__ proto_out)
{
    const int row  = blockIdx.x * 4 + (threadIdx.x >> 6);
    const int lane = threadIdx.x & 63;

    const int g    = row >> 4;          // proto group 0..31
    const int l16p = row & 15;          // row within group

    const float4* src4 = (const float4*)(p + (size_t)row * K_DIM);
    float4* pout4 = (float4*)(proto_out + (size_t)row * K_DIM);

    float ssum = 0.0f;
#pragma unroll
    for (int j = 0; j < 3; ++j) {        // 192 float4 per row / 64 lanes
        const int idx = lane + j * 64;   // float4 index 0..191
        float4 v = src4[idx];
        ssum += v.x * v.x + v.y * v.y + v.z * v.z + v.w * v.w;
        ushort4 b;
        b.x = f2bf(v.x); b.y = f2bf(v.y); b.z = f2bf(v.z); b.w = f2bf(v.w);
        // fragment-major: element k -> block (g*24 + k>>5), slot
        // ((k>>3)&3)*16 + l16p (lane id), sub-offset k&7.
        const int k0   = idx * 4;               // first element of this ushort4
        const int kk   = k0 >> 5;               // k-step 0..23
        const int quad = (k0 >> 3) & 3;         // k-slice 0..3
        const int j0   = k0 & 7;                // 0 or 4
        const int dst  = (g * 24 + kk) * 512 + quad * 128 + l16p * 8 + j0;
        *(ushort4*)&b_bf[dst] = b;
        pout4[idx] = v;
    }
#pragma unroll
    for (int off = 32; off > 0; off >>= 1) ssum += __shfl_down(ssum, off);
    if (lane == 0) p_sq[row] = ssum;
}

__global__ __launch_bounds__(1024, 4) void dist_main(
    const float* __restrict__ X,             // [M,K] fp32 tokens
    const unsigned short* __restrict__ Bb,   // fragment-major bf16 protos (ws)
    const float* __restrict__ p_sq,          // [N] fp32
    float* __restrict__ out)                 // [M,N] fp32 distances
{
    __shared__ unsigned short lds_a[64 * ASTR];   // ~97 KB, full-K A stripe
    __shared__ float lds_xsq[64];

    const int tid  = threadIdx.x;
    const int wave = tid >> 6;           // 0..15
    const int lane = tid & 63;
    const int bm   = blockIdx.x << 6;    // 64-row A stripe
    const int wn   = wave << 5;          // this wave's 32-col slice of N
    const int quad = lane >> 4;          // 0..3
    const int l16  = lane & 15;

    // ---- staging mapping: 1024 thr, section = 64 rows x 96 float4 ----
    // per section: 6144 float4 / 1024 thr = 6 each, c4 = sec*96 + ac + 16*j
    const int ar = tid >> 4;             // row 0..63
    const int ac = tid & 15;             // float4 col base 0..15
    const float* aptr = X + (size_t)(bm + ar) * K_DIM;

    float asq = 0.0f;

    // ---- stage section 0 as one full burst (6 loads in flight) ----
#pragma unroll
    for (int j = 0; j < 6; ++j) {
        const int c4 = ac + 16 * j;      // float4 index 0..95
        float4 v = *(const float4*)(aptr + (size_t)c4 * 4);
        asq += v.x * v.x + v.y * v.y + v.z * v.z + v.w * v.w;
        ushort4 u;
        u.x = f2bf(v.x); u.y = f2bf(v.y); u.z = f2bf(v.z); u.w = f2bf(v.w);
        *(ushort4*)&lds_a[ar * ASTR + c4 * 4] = u;
    }
    __syncthreads();   // barrier 1: section 0 visible (compiler drains vmcnt)

    // ---- B init (issue BEFORE s1 so iteration-0 MFMA isn't poisoned) ----
    const unsigned short* bp = Bb + (size_t)lane * 8;
    const int gbase = (wave << 1) * 24;          // (wave*2)*24

    bf16x8 bcur[2], bnxt[2];
#pragma unroll
    for (int nt = 0; nt < 2; ++nt)
        bcur[nt] = *(const bf16x8*)(bp + (size_t)(gbase + nt * 24) * 512);

    // ---- issue section-1 global loads; PIN the issue point ----
    float4 s1[6];
#pragma unroll
    for (int j = 0; j < 6; ++j)
        s1[j] = *(const float4*)(aptr + (size_t)(96 + ac + 16 * j) * 4);
    // SCHED_BARRIER(0): unmodeled side effects -- scheduler/MachineSinking
    // cannot move the loads above past this point. Issue = here; wait = at
    // first use (after K-loop section 0). This is the whole R16 change.
    __builtin_amdgcn_sched_barrier(0);

    const f32x4 zero = {0.0f, 0.0f, 0.0f, 0.0f};
    f32x4 acc[4][2];
#pragma unroll
    for (int mt = 0; mt < 4; ++mt) {
        acc[mt][0] = zero; acc[mt][1] = zero;
    }

    // ---- K-loop section 0: kc = 0..11 (s1 loads in flight underneath) ----
    for (int kc = 0; kc < KSEC; ++kc) {
#pragma unroll
        for (int nt = 0; nt < 2; ++nt)
            bnxt[nt] = *(const bf16x8*)(bp
                + (size_t)(gbase + nt * 24 + kc + 1) * 512);

        bf16x8 af[4];
        const int k0 = kc * BK;
#pragma unroll
        for (int mt = 0; mt < 4; ++mt)
            af[mt] = *(const bf16x8*)&lds_a[(mt * 16 + l16) * ASTR + k0 + quad * 8];

#pragma unroll
        for (int mt = 0; mt < 4; ++mt) {
            acc[mt][0] = __builtin_amdgcn_mfma_f32_16x16x32_bf16(
                af[mt], bcur[0], acc[mt][0], 0, 0, 0);
            acc[mt][1] = __builtin_amdgcn_mfma_f32_16x16x32_bf16(
                af[mt], bcur[1], acc[mt][1], 0, 0, 0);
        }
        bcur[0] = bnxt[0]; bcur[1] = bnxt[1];
    }

    // ---- convert + write section 1 (loads retired during loop 0) ----
#pragma unroll
    for (int j = 0; j < 6; ++j) {
        float4 v = s1[j];
        asq += v.x * v.x + v.y * v.y + v.z * v.z + v.w * v.w;
        ushort4 u;
        u.x = f2bf(v.x); u.y = f2bf(v.y); u.z = f2bf(v.z); u.w = f2bf(v.w);
        *(ushort4*)&lds_a[ar * ASTR + (96 + ac + 16 * j) * 4] = u;
    }
    __syncthreads();   // barrier 2: section 1 visible

    // ---- K-loop section 1: kc = 12..23 ----
    for (int kc = KSEC; kc < NSK; ++kc) {
        if (kc + 1 < NSK) {
#pragma unroll
            for (int nt = 0; nt < 2; ++nt)
                bnxt[nt] = *(const bf16x8*)(bp
                    + (size_t)(gbase + nt * 24 + kc + 1) * 512);
        }

        bf16x8 af[4];
        const int k0 = kc * BK;
#pragma unroll
        for (int mt = 0; mt < 4; ++mt)
            af[mt] = *(const bf16x8*)&lds_a[(mt * 16 + l16) * ASTR + k0 + quad * 8];

#pragma unroll
        for (int mt = 0; mt < 4; ++mt) {
            acc[mt][0] = __builtin_amdgcn_mfma_f32_16x16x32_bf16(
                af[mt], bcur[0], acc[mt][0], 0, 0, 0);
            acc[mt][1] = __builtin_amdgcn_mfma_f32_16x16x32_bf16(
                af[mt], bcur[1], acc[mt][1], 0, 0, 0);
        }
        bcur[0] = bnxt[0]; bcur[1] = bnxt[1];
    }

    // ---- x_sq: reduce over the 16 staging threads of each row ----
#pragma unroll
    for (int off = 1; off < 16; off <<= 1) asq += __shfl_xor(asq, off);
    if (ac == 0) lds_xsq[ar] = asq;
    __syncthreads();

    // ---- epilogue: C/D layout col = lane&15, row = quad*4 + i ----
    float ps[2];
#pragma unroll
    for (int nt = 0; nt < 2; ++nt) ps[nt] = p_sq[wn + nt * 16 + l16];

#pragma unroll
    for (int mt = 0; mt < 4; ++mt) {
#pragma unroll
        for (int i = 0; i < 4; ++i) {
            const int lr = mt * 16 + quad * 4 + i;   // local row 0..63
            const float xs = lds_xsq[lr];
            float* orow = out + (size_t)(bm + lr) * N_PROT + wn + l16;
#pragma unroll
            for (int nt = 0; nt < 2; ++nt)
                orow[nt * 16] = xs + ps[nt] - 2.0f * acc[mt][nt][i];
        }
    }
}

extern "C" void kernel_launch(void* const* d_in, const int* in_sizes, int n_in,
                              void* d_out, int out_size, void* d_ws, size_t ws_size,
                              hipStream_t stream) {
    const float* inputs = (const float*)d_in[0];   // [32,512,768] fp32
    const float* protos = (const float*)d_in[1];   // [512,768]    fp32
    float* out = (float*)d_out;
    float* proto_out = out + (size_t)M_TOK * N_PROT;   // second tuple element

    // ws layout: b_bf 512*768*2 = 786,432 B (fragment-major) ; p_sq 2,048 B
    char* ws = (char*)d_ws;
    unsigned short* b_bf = (unsigned short*)ws;
    float* p_sq = (float*)(ws + 786432);

    prep_b<<<128, 256, 0, stream>>>(protos, b_bf, p_sq, proto_out);
    dist_main<<<M_TOK / 64, 1024, 0, stream>>>(inputs, b_bf, p_sq, out);
}